// Round 5
// baseline (286.115 us; speedup 1.0000x reference)
//
#include <hip/hip_runtime.h>
#include <hip/hip_bf16.h>

typedef __bf16 bf16x8 __attribute__((ext_vector_type(8)));
typedef float f32x4 __attribute__((ext_vector_type(4)));
typedef unsigned short ushort8 __attribute__((ext_vector_type(8)));

#define DEVINL static __device__ __forceinline__

DEVINL unsigned f2bf(float f){
  unsigned u = __float_as_uint(f);
  return (u + 0x7fffu + ((u >> 16) & 1u)) >> 16;
}

DEVINL f32x4 MFMA(bf16x8 a, bf16x8 b, f32x4 c){
  return __builtin_amdgcn_mfma_f32_16x16x32_bf16(a, b, c, 0, 0, 0);
}

typedef const __attribute__((address_space(1))) unsigned int* gas_t;
typedef __attribute__((address_space(3))) unsigned int* las_t;
DEVINL void gload_lds16(const void* g, void* l){
  __builtin_amdgcn_global_load_lds((gas_t)g, (las_t)l, 16, 0, 0);
}

// ---------- fp32 -> bf16 pack (n multiple of 4) ----------
__global__ void k_cvt(const float* __restrict__ s, unsigned short* __restrict__ d, int n){
  int i = (blockIdx.x * blockDim.x + threadIdx.x) * 4;
  if (i >= n) return;
  float4 v = *(const float4*)(s + i);
  ushort4 o;
  o.x = (unsigned short)f2bf(v.x); o.y = (unsigned short)f2bf(v.y);
  o.z = (unsigned short)f2bf(v.z); o.w = (unsigned short)f2bf(v.w);
  *(ushort4*)(d + i) = o;
}

// ---------- fused transposes: WQ/WK/WV (256x2048) + Wout (2048x256), fp32 -> bf16 [C][R] ----------
__global__ void k_tr4(const float* __restrict__ WQ, const float* __restrict__ WK,
                      const float* __restrict__ WV, const float* __restrict__ Wout,
                      unsigned short* __restrict__ wT, unsigned short* __restrict__ woT){
  __shared__ float t[32][33];
  int id = blockIdx.x;
  const float* s; unsigned short* d; int R, C, tile;
  if (id < 1536){
    int z = id >> 9; tile = id & 511;
    s = (z == 0) ? WQ : ((z == 1) ? WK : WV);
    d = wT + z * 524288; R = 256; C = 2048;
  } else {
    tile = id - 1536; s = Wout; d = woT; R = 2048; C = 256;
  }
  int tilesX = C >> 5;
  int c0 = (tile % tilesX) * 32, r0 = (tile / tilesX) * 32;
  int tx = threadIdx.x, ty = threadIdx.y;
  #pragma unroll
  for (int k2 = 0; k2 < 4; k2++) t[ty + 8*k2][tx] = s[(r0 + ty + 8*k2) * C + c0 + tx];
  __syncthreads();
  #pragma unroll
  for (int k2 = 0; k2 < 4; k2++) d[(c0 + ty + 8*k2) * R + r0 + tx] = (unsigned short)f2bf(t[tx][ty + 8*k2]);
}

// ---------- QKV projection: [8192,256] @ [256,2048] -> q,k [8192,2048], val -> vT[b,h,c,s] ----------
__global__ __launch_bounds__(256, 2) void k_qkv(const unsigned short* __restrict__ vb,
    const unsigned short* __restrict__ wT,
    unsigned short* __restrict__ qo, unsigned short* __restrict__ ko, unsigned short* __restrict__ vTo){
  __shared__ unsigned short As[128 * 72];
  __shared__ unsigned short Bs[128 * 72];
  int tid = threadIdx.x;
  int lane = tid & 63, wid = tid >> 6;
  int lr = lane & 15, lg = lane >> 4;
  int wm = (wid >> 1) * 64, wn = (wid & 1) * 64;
  int bn = blockIdx.x, bm = blockIdx.y, z = blockIdx.z;

  const unsigned short* Ag = vb + (bm * 128) * 256;
  const unsigned short* Bg = wT + z * (2048 * 256) + (bn * 128) * 256;

  f32x4 acc[4][4] = {};
  for (int kt = 0; kt < 4; kt++){
    ushort8 ra[4], rb[4];
    #pragma unroll
    for (int p = 0; p < 4; p++){
      int idx = p * 256 + tid; int row = idx >> 3, ch = idx & 7;
      ra[p] = *(const ushort8*)(Ag + row * 256 + kt * 64 + ch * 8);
      rb[p] = *(const ushort8*)(Bg + row * 256 + kt * 64 + ch * 8);
    }
    __syncthreads();
    #pragma unroll
    for (int p = 0; p < 4; p++){
      int idx = p * 256 + tid; int row = idx >> 3, ch = idx & 7;
      *(ushort8*)(As + row * 72 + ch * 8) = ra[p];
      *(ushort8*)(Bs + row * 72 + ch * 8) = rb[p];
    }
    __syncthreads();
    #pragma unroll
    for (int kf = 0; kf < 2; kf++){
      bf16x8 af[4], bfr[4];
      #pragma unroll
      for (int mf = 0; mf < 4; mf++) af[mf]  = *(const bf16x8*)(As + (wm + mf*16 + lr) * 72 + kf*32 + lg*8);
      #pragma unroll
      for (int nf = 0; nf < 4; nf++) bfr[nf] = *(const bf16x8*)(Bs + (wn + nf*16 + lr) * 72 + kf*32 + lg*8);
      #pragma unroll
      for (int mf = 0; mf < 4; mf++)
        #pragma unroll
        for (int nf = 0; nf < 4; nf++)
          acc[mf][nf] = MFMA(af[mf], bfr[nf], acc[mf][nf]);
    }
  }
  if (z < 2){
    unsigned short* dst = z ? ko : qo;
    #pragma unroll
    for (int mf = 0; mf < 4; mf++)
      #pragma unroll
      for (int nf = 0; nf < 4; nf++){
        int mg = bm*128 + wm + mf*16 + lg*4;
        int ng = bn*128 + wn + nf*16 + lr;
        #pragma unroll
        for (int r2 = 0; r2 < 4; r2++) dst[(mg + r2) * 2048 + ng] = (unsigned short)f2bf(acc[mf][nf][r2]);
      }
  } else {
    #pragma unroll
    for (int mf = 0; mf < 4; mf++)
      #pragma unroll
      for (int nf = 0; nf < 4; nf++){
        int mg = bm*128 + wm + mf*16 + lg*4;
        int ng = bn*128 + wn + nf*16 + lr;
        int bb = mg >> 11, s = mg & 2047, hh = ng >> 8, cc = ng & 255;
        uint2 w;
        w.x = f2bf(acc[mf][nf][0]) | (f2bf(acc[mf][nf][1]) << 16);
        w.y = f2bf(acc[mf][nf][2]) | (f2bf(acc[mf][nf][3]) << 16);
        *(uint2*)(vTo + (size_t)((bb*8 + hh) * 256 + cc) * 2048 + s) = w;
      }
  }
}

// ---------- flash attention: 8 waves/block, 16 q-rows/wave, LDS-shared K/V double-buffer ----------
// Same proven sync skeleton as R4 (dbuf + vmcnt(0) + 1 barrier/tile); q split 8 ways
// so 512 blocks x 8 waves = 16 waves/CU (4/SIMD) at the same 72KB LDS footprint.
__global__ __launch_bounds__(512, 4) void k_attn(const unsigned short* __restrict__ q,
    const unsigned short* __restrict__ kk, const unsigned short* __restrict__ vT,
    unsigned short* __restrict__ u){
  __shared__ unsigned short Ks[2][8192];
  __shared__ unsigned short Vs[2][8192];
  __shared__ unsigned short Ps[8][512];
  int tid = threadIdx.x;
  int lane = tid & 63, wid = tid >> 6;
  int lr = lane & 15, lg = lane >> 4;
  // XCD-chunked swizzle: 512 blocks = 8 XCD x 64; each XCD gets 4 contiguous (b,h) pairs
  int g = (blockIdx.x & 7) * 64 + (blockIdx.x >> 3);
  int bh = g >> 4, qt = g & 15;
  int b = bh >> 3, h = bh & 7;
  int q0 = qt * 128;

  const char* kgB = (const char*)(kk + (size_t)b * 2048 * 2048 + h * 256);
  const char* vgB = (const char*)(vT + (size_t)(b * 8 + h) * 256 * 2048);
  const unsigned short* qg = q + (size_t)(b * 2048 + q0 + wid * 16) * 2048 + h * 256;

  // staging: 2048 x 16B chunks per tile; waves 0-3 -> K, waves 4-7 -> V (4 issues each)
  const char* sp[4];
  bool isK = wid < 4;
  long stepB = isK ? 131072 : 64;   // K: 32 rows * 4096B ; V: 32 t * 2B
  #pragma unroll
  for (int j = 0; j < 4; j++){
    if (isK){
      int c = wid * 256 + j * 64 + lane;
      int row = c >> 5, slot = c & 31;
      sp[j] = kgB + (size_t)row * 4096 + ((slot ^ (row & 7)) * 16);
    } else {
      int c2 = (wid - 4) * 256 + j * 64 + lane;
      int crow = c2 >> 2, slot = c2 & 3;
      sp[j] = vgB + (size_t)crow * 4096 + ((slot ^ (crow & 3)) * 16);
    }
  }
  int wbase = (isK ? wid : (wid - 4)) * 4096;   // byte offset of this wave's quarter-tile
  auto stage = [&](int buf){
    char* db = (char*)(isK ? &Ks[buf][0] : &Vs[buf][0]) + wbase;
    #pragma unroll
    for (int j = 0; j < 4; j++){
      gload_lds16(sp[j], db + j * 1024);
      sp[j] += stepB;
    }
  };

  stage(0);

  // Q -> registers: wave-private 16 rows x 256 (B-operand frags)
  bf16x8 qreg[8];
  #pragma unroll
  for (int kf = 0; kf < 8; kf++)
    qreg[kf] = *(const bf16x8*)(qg + (size_t)lr * 2048 + kf * 32 + lg * 8);

  f32x4 acc[16] = {};
  float lpart = 0.f;
  const float SC2   = 0.25503510f;    // (1/sqrt(32)) * log2(e)
  const float SHIFT = -11.5415603f;   // -8 * log2(e)

  for (int t0 = 0; t0 < 64; t0++){
    int cur = t0 & 1;
    asm volatile("s_waitcnt vmcnt(0)" ::: "memory");   // own stage loads (issued a full tile ago)
    __builtin_amdgcn_s_barrier();                      // all waves' loads visible; prev compute done
    if (t0 + 1 < 64) stage(cur ^ 1);                   // issue-early: lands during this compute
    const unsigned short* Ksb = Ks[cur];
    const unsigned short* Vsb = Vs[cur];
    unsigned short* Psw = Ps[wid];

    // QK^T (swapped: A=K so q-rows are lane-local in C cols)
    f32x4 pt[2] = {};   // [tf]; row=t, col=q (16 q-rows of this wave)
    __builtin_amdgcn_s_setprio(1);
    #pragma unroll
    for (int kf = 0; kf < 8; kf++){
      #pragma unroll
      for (int tf = 0; tf < 2; tf++){
        int row = tf * 16 + lr;
        bf16x8 ka = *(const bf16x8*)(Ksb + row * 256 + (((kf * 4 + lg) ^ (row & 7)) * 8));
        pt[tf] = MFMA(ka, qreg[kf], pt[tf]);
      }
    }
    __builtin_amdgcn_s_setprio(0);
    // P = exp2(s*SC2 + SHIFT) = e^(s*SC - 8); accumulate per-lane partial row sums
    {
      float s0 = 0.f, s1 = 0.f;
      #pragma unroll
      for (int tf = 0; tf < 2; tf++)
        #pragma unroll
        for (int r2 = 0; r2 < 4; r2++){
          float e = __builtin_amdgcn_exp2f(fmaf(pt[tf][r2], SC2, SHIFT));
          pt[tf][r2] = e;
          if (r2 & 1) s1 += e; else s0 += e;
        }
      lpart += s0 + s1;
    }
    // P -> bf16 -> wave-private swizzled LDS (transpose S^T -> A-frag layout)
    {
      int qrow = lr;
      #pragma unroll
      for (int tf = 0; tf < 2; tf++){
        uint2 w;
        w.x = f2bf(pt[tf][0]) | (f2bf(pt[tf][1]) << 16);
        w.y = f2bf(pt[tf][2]) | (f2bf(pt[tf][3]) << 16);
        *(uint2*)(Psw + qrow * 32 + (((tf * 2 + (lg >> 1)) ^ (qrow & 3)) * 8) + (lg & 1) * 4) = w;
      }
    }
    // PV: acc[c] += P[qrow][t] * V[t][c]
    bf16x8 pa = *(const bf16x8*)(Psw + lr * 32 + ((lg ^ (lr & 3)) * 8));
    __builtin_amdgcn_s_setprio(1);
    #pragma unroll
    for (int nf = 0; nf < 16; nf++){
      int crow = nf * 16 + lr;
      bf16x8 vf = *(const bf16x8*)(Vsb + crow * 32 + ((lg ^ (crow & 3)) * 8));
      acc[nf] = MFMA(pa, vf, acc[nf]);
    }
    __builtin_amdgcn_s_setprio(0);
  }
  // final l reduction (once per kernel, not per tile)
  lpart += __shfl_xor(lpart, 16);
  lpart += __shfl_xor(lpart, 32);
  // epilogue: O /= l, write u [8192][2048]
  {
    float inv = 1.f / lpart;
    float i4[4];
    #pragma unroll
    for (int r2 = 0; r2 < 4; r2++) i4[r2] = __shfl(inv, lg * 4 + r2);
    #pragma unroll
    for (int nf = 0; nf < 16; nf++)
      #pragma unroll
      for (int r2 = 0; r2 < 4; r2++){
        int s = q0 + wid * 16 + lg * 4 + r2;
        int c = nf * 16 + lr;
        u[(size_t)(b * 2048 + s) * 2048 + h * 256 + c] = (unsigned short)f2bf(acc[nf][r2] * i4[r2]);
      }
  }
}

// ---------- output projection: [8192,2048] @ [2048,256] + bias -> fp32 ----------
__global__ __launch_bounds__(256, 2) void k_out(const unsigned short* __restrict__ u,
    const unsigned short* __restrict__ woT, const float* __restrict__ bout, float* __restrict__ out){
  __shared__ unsigned short As[64 * 72];
  __shared__ unsigned short Bs[64 * 72];
  int tid = threadIdx.x;
  int lane = tid & 63, wid = tid >> 6;
  int lr = lane & 15, lg = lane >> 4;
  int wm = (wid >> 1) * 32, wn = (wid & 1) * 32;
  int bn = blockIdx.x, bm = blockIdx.y;
  const unsigned short* Ag = u + (size_t)(bm * 64) * 2048;
  const unsigned short* Bg = woT + (size_t)(bn * 64) * 2048;
  f32x4 acc[2][2] = {};
  for (int kt = 0; kt < 32; kt++){
    ushort8 ra[2], rb[2];
    #pragma unroll
    for (int p = 0; p < 2; p++){
      int idx = p * 256 + tid; int row = idx >> 3, ch = idx & 7;
      ra[p] = *(const ushort8*)(Ag + (size_t)row * 2048 + kt*64 + ch*8);
      rb[p] = *(const ushort8*)(Bg + (size_t)row * 2048 + kt*64 + ch*8);
    }
    __syncthreads();
    #pragma unroll
    for (int p = 0; p < 2; p++){
      int idx = p * 256 + tid; int row = idx >> 3, ch = idx & 7;
      *(ushort8*)(As + row * 72 + ch * 8) = ra[p];
      *(ushort8*)(Bs + row * 72 + ch * 8) = rb[p];
    }
    __syncthreads();
    #pragma unroll
    for (int kf = 0; kf < 2; kf++){
      bf16x8 a0 = *(const bf16x8*)(As + (wm + lr) * 72      + kf*32 + lg*8);
      bf16x8 a1 = *(const bf16x8*)(As + (wm + 16 + lr) * 72 + kf*32 + lg*8);
      bf16x8 b0 = *(const bf16x8*)(Bs + (wn + lr) * 72      + kf*32 + lg*8);
      bf16x8 b1 = *(const bf16x8*)(Bs + (wn + 16 + lr) * 72 + kf*32 + lg*8);
      acc[0][0] = MFMA(a0, b0, acc[0][0]); acc[0][1] = MFMA(a0, b1, acc[0][1]);
      acc[1][0] = MFMA(a1, b0, acc[1][0]); acc[1][1] = MFMA(a1, b1, acc[1][1]);
    }
  }
  #pragma unroll
  for (int mf = 0; mf < 2; mf++)
    #pragma unroll
    for (int nf = 0; nf < 2; nf++){
      int mg = bm*64 + wm + mf*16 + lg*4;
      int ng = bn*64 + wn + nf*16 + lr;
      #pragma unroll
      for (int r2 = 0; r2 < 4; r2++) out[(size_t)(mg + r2) * 256 + ng] = acc[mf][nf][r2] + bout[ng];
    }
}

extern "C" void kernel_launch(void* const* d_in, const int* in_sizes, int n_in,
                              void* d_out, int out_size, void* d_ws, size_t ws_size,
                              hipStream_t stream){
  const float* v    = (const float*)d_in[0];
  const float* WQ   = (const float*)d_in[1];
  const float* WK   = (const float*)d_in[2];
  const float* WV   = (const float*)d_in[3];
  const float* Wout = (const float*)d_in[4];
  const float* bout = (const float*)d_in[5];
  char* ws = (char*)d_ws;
  unsigned short* vb  = (unsigned short*)(ws);                     // v bf16      [8192][256]   4 MB
  unsigned short* wT  = (unsigned short*)(ws + (4u  << 20));       // WQ/WK/WV^T  [3][2048][256] 3 MB
  unsigned short* woT = (unsigned short*)(ws + (7u  << 20));       // Wout^T      [256][2048]   1 MB
  unsigned short* qb  = (unsigned short*)(ws + (8u  << 20));       // q  [8192][2048] 32 MB
  unsigned short* kb  = (unsigned short*)(ws + (40u << 20));       // k  [8192][2048] 32 MB
  unsigned short* vTb = (unsigned short*)(ws + (72u << 20));       // vT [b,h,c,s]   32 MB
  unsigned short* ub  = (unsigned short*)(ws + (104u << 20));      // u  [8192][2048] 32 MB
  float* out = (float*)d_out;

  k_cvt<<<2048, 256, 0, stream>>>(v, vb, 2097152);
  k_tr4<<<2048, dim3(32, 8), 0, stream>>>(WQ, WK, WV, Wout, wT, woT);
  k_qkv<<<dim3(16, 64, 3), 256, 0, stream>>>(vb, wT, qb, kb, vTb);
  k_attn<<<512, 512, 0, stream>>>(qb, kb, vTb, ub);
  k_out<<<dim3(4, 128), 256, 0, stream>>>(ub, woT, bout, out);
}

// Round 7
// 207.225 us; speedup vs baseline: 1.3807x; 1.3807x over previous
//
#include <hip/hip_runtime.h>
#include <hip/hip_bf16.h>

typedef __bf16 bf16x8 __attribute__((ext_vector_type(8)));
typedef float f32x4 __attribute__((ext_vector_type(4)));
typedef unsigned short ushort8 __attribute__((ext_vector_type(8)));

#define DEVINL static __device__ __forceinline__

DEVINL unsigned f2bf(float f){
  unsigned u = __float_as_uint(f);
  return (u + 0x7fffu + ((u >> 16) & 1u)) >> 16;
}

DEVINL f32x4 MFMA(bf16x8 a, bf16x8 b, f32x4 c){
  return __builtin_amdgcn_mfma_f32_16x16x32_bf16(a, b, c, 0, 0, 0);
}

typedef const __attribute__((address_space(1))) unsigned int* gas_t;
typedef __attribute__((address_space(3))) unsigned int* las_t;
DEVINL void gload_lds16(const void* g, void* l){
  __builtin_amdgcn_global_load_lds((gas_t)g, (las_t)l, 16, 0, 0);
}

// T12 primitives. Verified semantics (gfx950 ISA):
//   sw32(a,b): a=[a.row0, b.row0], b=[a.row1, b.row1]   (row = 32 lanes)
//   sw16(a,b): a=[a.g0, b.g0, a.g2, b.g2], b=[a.g1, b.g1, a.g3, b.g3]  (g = 16 lanes)
DEVINL unsigned cvtpk(float lo, float hi){
  unsigned r; asm("v_cvt_pk_bf16_f32 %0, %1, %2" : "=v"(r) : "v"(lo), "v"(hi)); return r;
}
DEVINL void sw32(unsigned &a, unsigned &b){ asm("v_permlane32_swap_b32 %0, %1" : "+v"(a), "+v"(b)); }
DEVINL void sw16(unsigned &a, unsigned &b){ asm("v_permlane16_swap_b32 %0, %1" : "+v"(a), "+v"(b)); }

// ---------- fp32 -> bf16 pack (n multiple of 4) ----------
__global__ void k_cvt(const float* __restrict__ s, unsigned short* __restrict__ d, int n){
  int i = (blockIdx.x * blockDim.x + threadIdx.x) * 4;
  if (i >= n) return;
  float4 v = *(const float4*)(s + i);
  ushort4 o;
  o.x = (unsigned short)f2bf(v.x); o.y = (unsigned short)f2bf(v.y);
  o.z = (unsigned short)f2bf(v.z); o.w = (unsigned short)f2bf(v.w);
  *(ushort4*)(d + i) = o;
}

// ---------- fused transposes: WQ/WK/WV (256x2048) + Wout (2048x256), fp32 -> bf16 [C][R] ----------
__global__ void k_tr4(const float* __restrict__ WQ, const float* __restrict__ WK,
                      const float* __restrict__ WV, const float* __restrict__ Wout,
                      unsigned short* __restrict__ wT, unsigned short* __restrict__ woT){
  __shared__ float t[32][33];
  int id = blockIdx.x;
  const float* s; unsigned short* d; int R, C, tile;
  if (id < 1536){
    int z = id >> 9; tile = id & 511;
    s = (z == 0) ? WQ : ((z == 1) ? WK : WV);
    d = wT + z * 524288; R = 256; C = 2048;
  } else {
    tile = id - 1536; s = Wout; d = woT; R = 2048; C = 256;
  }
  int tilesX = C >> 5;
  int c0 = (tile % tilesX) * 32, r0 = (tile / tilesX) * 32;
  int tx = threadIdx.x, ty = threadIdx.y;
  #pragma unroll
  for (int k2 = 0; k2 < 4; k2++) t[ty + 8*k2][tx] = s[(r0 + ty + 8*k2) * C + c0 + tx];
  __syncthreads();
  #pragma unroll
  for (int k2 = 0; k2 < 4; k2++) d[(c0 + ty + 8*k2) * R + r0 + tx] = (unsigned short)f2bf(t[tx][ty + 8*k2]);
}

// ---------- QKV projection: [8192,256] @ [256,2048] -> q,k [8192,2048], val -> vT[b,h,c,s] ----------
__global__ __launch_bounds__(256, 2) void k_qkv(const unsigned short* __restrict__ vb,
    const unsigned short* __restrict__ wT,
    unsigned short* __restrict__ qo, unsigned short* __restrict__ ko, unsigned short* __restrict__ vTo){
  __shared__ unsigned short As[128 * 72];
  __shared__ unsigned short Bs[128 * 72];
  int tid = threadIdx.x;
  int lane = tid & 63, wid = tid >> 6;
  int lr = lane & 15, lg = lane >> 4;
  int wm = (wid >> 1) * 64, wn = (wid & 1) * 64;
  int bn = blockIdx.x, bm = blockIdx.y, z = blockIdx.z;

  const unsigned short* Ag = vb + (bm * 128) * 256;
  const unsigned short* Bg = wT + z * (2048 * 256) + (bn * 128) * 256;

  f32x4 acc[4][4] = {};
  for (int kt = 0; kt < 4; kt++){
    ushort8 ra[4], rb[4];
    #pragma unroll
    for (int p = 0; p < 4; p++){
      int idx = p * 256 + tid; int row = idx >> 3, ch = idx & 7;
      ra[p] = *(const ushort8*)(Ag + row * 256 + kt * 64 + ch * 8);
      rb[p] = *(const ushort8*)(Bg + row * 256 + kt * 64 + ch * 8);
    }
    __syncthreads();
    #pragma unroll
    for (int p = 0; p < 4; p++){
      int idx = p * 256 + tid; int row = idx >> 3, ch = idx & 7;
      *(ushort8*)(As + row * 72 + ch * 8) = ra[p];
      *(ushort8*)(Bs + row * 72 + ch * 8) = rb[p];
    }
    __syncthreads();
    #pragma unroll
    for (int kf = 0; kf < 2; kf++){
      bf16x8 af[4], bfr[4];
      #pragma unroll
      for (int mf = 0; mf < 4; mf++) af[mf]  = *(const bf16x8*)(As + (wm + mf*16 + lr) * 72 + kf*32 + lg*8);
      #pragma unroll
      for (int nf = 0; nf < 4; nf++) bfr[nf] = *(const bf16x8*)(Bs + (wn + nf*16 + lr) * 72 + kf*32 + lg*8);
      #pragma unroll
      for (int mf = 0; mf < 4; mf++)
        #pragma unroll
        for (int nf = 0; nf < 4; nf++)
          acc[mf][nf] = MFMA(af[mf], bfr[nf], acc[mf][nf]);
    }
  }
  if (z < 2){
    unsigned short* dst = z ? ko : qo;
    #pragma unroll
    for (int mf = 0; mf < 4; mf++)
      #pragma unroll
      for (int nf = 0; nf < 4; nf++){
        int mg = bm*128 + wm + mf*16 + lg*4;
        int ng = bn*128 + wn + nf*16 + lr;
        #pragma unroll
        for (int r2 = 0; r2 < 4; r2++) dst[(mg + r2) * 2048 + ng] = (unsigned short)f2bf(acc[mf][nf][r2]);
      }
  } else {
    #pragma unroll
    for (int mf = 0; mf < 4; mf++)
      #pragma unroll
      for (int nf = 0; nf < 4; nf++){
        int mg = bm*128 + wm + mf*16 + lg*4;
        int ng = bn*128 + wn + nf*16 + lr;
        int bb = mg >> 11, s = mg & 2047, hh = ng >> 8, cc = ng & 255;
        uint2 w;
        w.x = f2bf(acc[mf][nf][0]) | (f2bf(acc[mf][nf][1]) << 16);
        w.y = f2bf(acc[mf][nf][2]) | (f2bf(acc[mf][nf][3]) << 16);
        *(uint2*)(vTo + (size_t)((bb*8 + hh) * 256 + cc) * 2048 + s) = w;
      }
  }
}

// ---------- flash attention: 4 waves/block (R4 skeleton), P in registers, conflict-free V ----------
// K LDS: 32 rows x 512B, slot ^= row&7 (pre-swizzled global source; linear gload_lds dest).
// V LDS: slot S = (crow>>3)*32 + ts*8 + ((crow&7)^(2*ts)).
// P: QK^T output -> PV A-frags entirely in registers (cvt_pk + permlane butterfly):
//   held: A=(t 4lg,4lg+1) B=(4lg+2,4lg+3) C=(16+4lg,16+4lg+1) D=(16+4lg+2,16+4lg+3)
//   need word j @ lg: t {8lg+2j, 8lg+2j+1}
//   sw32(A,C);sw16(A,C) => A=(A0,A2,C0,C2)=w0, C=(A1,A3,C1,C3)=w2; B/D likewise -> w1,w3.
__global__ __launch_bounds__(256, 2) void k_attn(const unsigned short* __restrict__ q,
    const unsigned short* __restrict__ kk, const unsigned short* __restrict__ vT,
    unsigned short* __restrict__ u){
  __shared__ unsigned short Ks[2][8192];
  __shared__ unsigned short Vs[2][8192];
  int tid = threadIdx.x;
  int lane = tid & 63, wid = tid >> 6;
  int lr = lane & 15, lg = lane >> 4;
  // XCD-chunked swizzle: 512 blocks = 8 XCD x 64; each XCD gets 4 contiguous (b,h) pairs
  int g = (blockIdx.x & 7) * 64 + (blockIdx.x >> 3);
  int bh = g >> 4, qt = g & 15;
  int b = bh >> 3, h = bh & 7;
  int q0 = qt * 128;

  const char* kgB = (const char*)(kk + (size_t)b * 2048 * 2048 + h * 256);
  const char* vgB = (const char*)(vT + (size_t)(b * 8 + h) * 256 * 2048);
  const unsigned short* qg = q + (size_t)(b * 2048 + q0 + wid * 32) * 2048 + h * 256;

  // stage one K/V tile (32 KB): 2048 chunks of 16B; waves 0,1 -> K, waves 2,3 -> V
  const char* sp[8];
  bool isK = wid < 2;
  long stepB = isK ? 131072 : 64;   // K: 32 rows * 4096B ; V: 32 t * 2B
  #pragma unroll
  for (int j = 0; j < 8; j++){
    if (isK){
      int c = wid * 512 + j * 64 + lane;
      int row = c >> 5, slot = c & 31;
      sp[j] = kgB + (size_t)row * 4096 + ((slot ^ (row & 7)) * 16);
    } else {
      int c2 = (wid - 2) * 512 + j * 64 + lane;
      int blk = c2 >> 5, ts = (c2 >> 3) & 3, low3 = c2 & 7;
      int crow = blk * 8 + (low3 ^ (ts * 2));
      sp[j] = vgB + (size_t)crow * 4096 + ts * 16;
    }
  }
  int wbase = (wid & 1) * 8192;     // byte offset of this wave's half-tile in LDS
  auto stage = [&](int buf){
    char* db = (char*)(isK ? &Ks[buf][0] : &Vs[buf][0]) + wbase;
    #pragma unroll
    for (int j = 0; j < 8; j++){
      gload_lds16(sp[j], db + j * 1024);
      sp[j] += stepB;
    }
  };

  stage(0);

  // Q -> registers: wave-private 32 rows x 256 (B-operand frags)
  bf16x8 qreg[2][8];
  #pragma unroll
  for (int qf = 0; qf < 2; qf++)
    #pragma unroll
    for (int kf = 0; kf < 8; kf++)
      qreg[qf][kf] = *(const bf16x8*)(qg + (size_t)(qf * 16 + lr) * 2048 + kf * 32 + lg * 8);

  f32x4 acc[2][16] = {};
  float lpart[2] = {0.f, 0.f};
  const float SC2   = 0.25503510f;    // (1/sqrt(32)) * log2(e)
  const float SHIFT = -11.5415603f;   // -8 * log2(e)

  // loop-invariant addressing
  int xA = (lg ^ (lr & 7)) * 16;                                   // K swizzle, kf even
  int vbase = (lr >> 3) * 512 + lg * 128 + (((lr & 7) ^ (lg * 2)) * 16);

  for (int t0 = 0; t0 < 64; t0++){
    int cur = t0 & 1;
    asm volatile("s_waitcnt vmcnt(0)" ::: "memory");   // own stage loads (issued a full tile ago)
    __builtin_amdgcn_s_barrier();                      // all waves' loads visible; prev compute done
    if (t0 + 1 < 64) stage(cur ^ 1);                   // issue-early: lands during this compute
    const char* Kc = (const char*)Ks[cur];
    const char* Vc = (const char*)Vs[cur];

    // QK^T (swapped: A=K so q-rows are lane-local in C cols)
    f32x4 pt[2][2] = {};   // [tf][qf]; row=t, col=q
    const char* ka0 = Kc + lr * 512 + xA;
    const char* ka1 = Kc + lr * 512 + (xA ^ 64);
    __builtin_amdgcn_s_setprio(1);
    #pragma unroll
    for (int kf2 = 0; kf2 < 4; kf2++){
      bf16x8 kE0 = *(const bf16x8*)(ka0 + kf2 * 128);            // tf=0, kf=2*kf2
      bf16x8 kO0 = *(const bf16x8*)(ka1 + kf2 * 128);            // tf=0, kf=2*kf2+1
      bf16x8 kE1 = *(const bf16x8*)(ka0 + 8192 + kf2 * 128);     // tf=1
      bf16x8 kO1 = *(const bf16x8*)(ka1 + 8192 + kf2 * 128);
      pt[0][0] = MFMA(kE0, qreg[0][2*kf2],   pt[0][0]);
      pt[0][1] = MFMA(kE0, qreg[1][2*kf2],   pt[0][1]);
      pt[1][0] = MFMA(kE1, qreg[0][2*kf2],   pt[1][0]);
      pt[1][1] = MFMA(kE1, qreg[1][2*kf2],   pt[1][1]);
      pt[0][0] = MFMA(kO0, qreg[0][2*kf2+1], pt[0][0]);
      pt[0][1] = MFMA(kO0, qreg[1][2*kf2+1], pt[0][1]);
      pt[1][0] = MFMA(kO1, qreg[0][2*kf2+1], pt[1][0]);
      pt[1][1] = MFMA(kO1, qreg[1][2*kf2+1], pt[1][1]);
    }
    __builtin_amdgcn_s_setprio(0);

    // P = exp2(s*SC2 + SHIFT) = e^(s*SC - 8); per-lane partial row sums
    bf16x8 pa[2];
    #pragma unroll
    for (int qf = 0; qf < 2; qf++){
      float s0 = 0.f, s1 = 0.f;
      #pragma unroll
      for (int tf = 0; tf < 2; tf++)
        #pragma unroll
        for (int r2 = 0; r2 < 4; r2++){
          float e = __builtin_amdgcn_exp2f(fmaf(pt[tf][qf][r2], SC2, SHIFT));
          pt[tf][qf][r2] = e;
          if (r2 & 1) s1 += e; else s0 += e;
        }
      lpart[qf] += s0 + s1;
      // register butterfly: P^T frag -> PV A-frag (no LDS). dst-first order (verified).
      unsigned A = cvtpk(pt[0][qf][0], pt[0][qf][1]);
      unsigned B = cvtpk(pt[0][qf][2], pt[0][qf][3]);
      unsigned C = cvtpk(pt[1][qf][0], pt[1][qf][1]);
      unsigned D = cvtpk(pt[1][qf][2], pt[1][qf][3]);
      sw32(A, C); sw32(B, D);
      sw16(A, C); sw16(B, D);
      union { unsigned w[4]; bf16x8 v; } cv;
      cv.w[0] = A; cv.w[1] = B; cv.w[2] = C; cv.w[3] = D;
      pa[qf] = cv.v;
    }

    // PV: acc[qrow][c] += P[qrow][t] * V[t][c]  (conflict-free V reads)
    __builtin_amdgcn_s_setprio(1);
    #pragma unroll
    for (int nf = 0; nf < 16; nf++){
      bf16x8 vf = *(const bf16x8*)(Vc + nf * 1024 + vbase);
      acc[0][nf] = MFMA(pa[0], vf, acc[0][nf]);
      acc[1][nf] = MFMA(pa[1], vf, acc[1][nf]);
    }
    __builtin_amdgcn_s_setprio(0);
  }
  // final l reduction (once per kernel, not per tile)
  #pragma unroll
  for (int qf = 0; qf < 2; qf++){
    lpart[qf] += __shfl_xor(lpart[qf], 16);
    lpart[qf] += __shfl_xor(lpart[qf], 32);
  }
  // epilogue: O /= l, write u [8192][2048]
  #pragma unroll
  for (int mf = 0; mf < 2; mf++){
    float inv = 1.f / lpart[mf];
    float i4[4];
    #pragma unroll
    for (int r2 = 0; r2 < 4; r2++) i4[r2] = __shfl(inv, lg * 4 + r2);
    #pragma unroll
    for (int nf = 0; nf < 16; nf++)
      #pragma unroll
      for (int r2 = 0; r2 < 4; r2++){
        int s = q0 + wid * 32 + mf * 16 + lg * 4 + r2;
        int c = nf * 16 + lr;
        u[(size_t)(b * 2048 + s) * 2048 + h * 256 + c] = (unsigned short)f2bf(acc[mf][nf][r2] * i4[r2]);
      }
  }
}

// ---------- output projection: [8192,2048] @ [2048,256] + bias -> fp32 ----------
__global__ __launch_bounds__(256, 2) void k_out(const unsigned short* __restrict__ u,
    const unsigned short* __restrict__ woT, const float* __restrict__ bout, float* __restrict__ out){
  __shared__ unsigned short As[64 * 72];
  __shared__ unsigned short Bs[64 * 72];
  int tid = threadIdx.x;
  int lane = tid & 63, wid = tid >> 6;
  int lr = lane & 15, lg = lane >> 4;
  int wm = (wid >> 1) * 32, wn = (wid & 1) * 32;
  int bn = blockIdx.x, bm = blockIdx.y;
  const unsigned short* Ag = u + (size_t)(bm * 64) * 2048;
  const unsigned short* Bg = woT + (size_t)(bn * 64) * 2048;
  f32x4 acc[2][2] = {};
  for (int kt = 0; kt < 32; kt++){
    ushort8 ra[2], rb[2];
    #pragma unroll
    for (int p = 0; p < 2; p++){
      int idx = p * 256 + tid; int row = idx >> 3, ch = idx & 7;
      ra[p] = *(const ushort8*)(Ag + (size_t)row * 2048 + kt*64 + ch*8);
      rb[p] = *(const ushort8*)(Bg + (size_t)row * 2048 + kt*64 + ch*8);
    }
    __syncthreads();
    #pragma unroll
    for (int p = 0; p < 2; p++){
      int idx = p * 256 + tid; int row = idx >> 3, ch = idx & 7;
      *(ushort8*)(As + row * 72 + ch * 8) = ra[p];
      *(ushort8*)(Bs + row * 72 + ch * 8) = rb[p];
    }
    __syncthreads();
    #pragma unroll
    for (int kf = 0; kf < 2; kf++){
      bf16x8 a0 = *(const bf16x8*)(As + (wm + lr) * 72      + kf*32 + lg*8);
      bf16x8 a1 = *(const bf16x8*)(As + (wm + 16 + lr) * 72 + kf*32 + lg*8);
      bf16x8 b0 = *(const bf16x8*)(Bs + (wn + lr) * 72      + kf*32 + lg*8);
      bf16x8 b1 = *(const bf16x8*)(Bs + (wn + 16 + lr) * 72 + kf*32 + lg*8);
      acc[0][0] = MFMA(a0, b0, acc[0][0]); acc[0][1] = MFMA(a0, b1, acc[0][1]);
      acc[1][0] = MFMA(a1, b0, acc[1][0]); acc[1][1] = MFMA(a1, b1, acc[1][1]);
    }
  }
  #pragma unroll
  for (int mf = 0; mf < 2; mf++)
    #pragma unroll
    for (int nf = 0; nf < 2; nf++){
      int mg = bm*64 + wm + mf*16 + lg*4;
      int ng = bn*64 + wn + nf*16 + lr;
      #pragma unroll
      for (int r2 = 0; r2 < 4; r2++) out[(size_t)(mg + r2) * 256 + ng] = acc[mf][nf][r2] + bout[ng];
    }
}

extern "C" void kernel_launch(void* const* d_in, const int* in_sizes, int n_in,
                              void* d_out, int out_size, void* d_ws, size_t ws_size,
                              hipStream_t stream){
  const float* v    = (const float*)d_in[0];
  const float* WQ   = (const float*)d_in[1];
  const float* WK   = (const float*)d_in[2];
  const float* WV   = (const float*)d_in[3];
  const float* Wout = (const float*)d_in[4];
  const float* bout = (const float*)d_in[5];
  char* ws = (char*)d_ws;
  unsigned short* vb  = (unsigned short*)(ws);                     // v bf16      [8192][256]   4 MB
  unsigned short* wT  = (unsigned short*)(ws + (4u  << 20));       // WQ/WK/WV^T  [3][2048][256] 3 MB
  unsigned short* woT = (unsigned short*)(ws + (7u  << 20));       // Wout^T      [256][2048]   1 MB
  unsigned short* qb  = (unsigned short*)(ws + (8u  << 20));       // q  [8192][2048] 32 MB
  unsigned short* kb  = (unsigned short*)(ws + (40u << 20));       // k  [8192][2048] 32 MB
  unsigned short* vTb = (unsigned short*)(ws + (72u << 20));       // vT [b,h,c,s]   32 MB
  unsigned short* ub  = (unsigned short*)(ws + (104u << 20));      // u  [8192][2048] 32 MB
  float* out = (float*)d_out;

  k_cvt<<<2048, 256, 0, stream>>>(v, vb, 2097152);
  k_tr4<<<2048, dim3(32, 8), 0, stream>>>(WQ, WK, WV, Wout, wT, woT);
  k_qkv<<<dim3(16, 64, 3), 256, 0, stream>>>(vb, wT, qb, kb, vTb);
  k_attn<<<512, 256, 0, stream>>>(qb, kb, vTb, ub);
  k_out<<<dim3(4, 128), 256, 0, stream>>>(ub, woT, bout, out);
}